// Round 11
// baseline (649.145 us; speedup 1.0000x reference)
//
#include <hip/hip_runtime.h>
#include <hip/hip_bf16.h>

#define BN 2
#define NH 12
#define NTOK 1600
#define NM 576
#define NS 1024
#define CD 768
#define HD 64

typedef unsigned short u16;
typedef unsigned int u32;
typedef __attribute__((ext_vector_type(8))) short short8;   // 8 bf16 (4 VGPRs)
typedef __attribute__((ext_vector_type(4))) float f32x4;    // MFMA C/D

__device__ __forceinline__ float fbits(u32 u) { return __uint_as_float(u); }
__device__ __forceinline__ u16 f2b(float f) {  // RNE f32->bf16
    u32 u = __float_as_uint(f);
    u32 r = u + 0x7FFFu + ((u >> 16) & 1u);
    return (u16)(r >> 16);
}
__device__ __forceinline__ float b2f(u16 s) { return fbits(((u32)s) << 16); }
__device__ __forceinline__ u32 flip16(u32 u) {  // order-preserving bf16 -> u16 key
    return (u & 0x8000u) ? (0xFFFFu & ~u) : (u | 0x8000u);
}
__device__ __forceinline__ float key2f(u32 k) {
    u32 b = (k & 0x8000u) ? (k & 0x7FFFu) : (0xFFFFu & ~k);
    return fbits(b << 16);
}
__device__ __forceinline__ float wave_red(float p) {
#pragma unroll
    for (int off = 1; off < 64; off <<= 1) p += __shfl_xor(p, off);
    return p;
}

__device__ __forceinline__ float dot768_ff(const float* __restrict__ a,
                                           const float* __restrict__ b) {
    float s = 0.f;
    for (int c = 0; c < CD; c += 4) {
        float4 fa = *(const float4*)(a + c);
        float4 fb = *(const float4*)(b + c);
        s += fa.x * fb.x + fa.y * fb.y + fa.z * fb.z + fa.w * fb.w;
    }
    return s;
}

// ---------------- small_dots: z24 (x tokens) + ziv/IDK (id tokens) ----------------
__global__ __launch_bounds__(256) void small_dots(const float* __restrict__ x,
                                                  const float* __restrict__ Aq,
                                                  float* __restrict__ zq,
                                                  const float* __restrict__ id,
                                                  const float* __restrict__ Aik,
                                                  const float* __restrict__ Aiv,
                                                  const float* __restrict__ Wik,
                                                  const float* __restrict__ bik,
                                                  const float* __restrict__ Bik,
                                                  float* __restrict__ ziv,
                                                  float* __restrict__ IDK) {
    __shared__ float dres[28];
    const int blk = blockIdx.x;
    const int tid = threadIdx.x, lane = tid & 63, wv = tid >> 6;
    if (blk < 3200) {  // x token: 24 LoRA dots
        const float* xr = x + (size_t)blk * CD;
#pragma unroll
        for (int t = 0; t < 6; ++t) {
            const int q = wv * 6 + t;
            const float* ar = Aq + (size_t)q * CD;
            float p = 0.f;
#pragma unroll
            for (int c = 0; c < 12; ++c) p += xr[lane + c * 64] * ar[lane + c * 64];
            p = wave_red(p);
            if (lane == 0) zq[(size_t)blk * 24 + q] = p;
        }
    } else {  // id token: 8 zik + 8 ziv + 12 W_idk dots, then IDK
        const int m = blk - 3200;
        const float* xr = id + (size_t)m * CD;
#pragma unroll
        for (int t = 0; t < 7; ++t) {
            const int q = wv * 7 + t;
            const float* ar = (q < 8) ? Aik + (size_t)q * CD
                            : (q < 16) ? Aiv + (size_t)(q - 8) * CD
                                       : Wik + (size_t)(q - 16) * CD;
            float p = 0.f;
#pragma unroll
            for (int c = 0; c < 12; ++c) p += xr[lane + c * 64] * ar[lane + c * 64];
            p = wave_red(p);
            if (lane == 0) dres[q] = p;
        }
        __syncthreads();
        if (tid < 8) ziv[(size_t)m * 8 + tid] = dres[8 + tid];
        if (tid < 12) {
            float v = dres[16 + tid] + bik[tid];
            float lo = 0.f;
#pragma unroll
            for (int r = 0; r < 8; ++r) lo += dres[r] * Bik[tid * 8 + r];
            IDK[m * NH + tid] = v + 0.125f * lo;
        }
    }
}

// ---------------- stage_all: every bf16 staging conversion in one launch ----------------
__global__ __launch_bounds__(256) void stage_all(const float* __restrict__ x,
                                                 const float* __restrict__ zq,
                                                 u16* __restrict__ x_aug,
                                                 const float* __restrict__ Wq,
                                                 const float* __restrict__ Bq,
                                                 u16* __restrict__ wqkv_aug,
                                                 const float* __restrict__ Wp,
                                                 const float* __restrict__ Bp,
                                                 u16* __restrict__ wproj_aug,
                                                 const float* __restrict__ mk,
                                                 u16* __restrict__ kseq,
                                                 const float* __restrict__ mv,
                                                 u16* __restrict__ vt,
                                                 const float* __restrict__ id,
                                                 const float* __restrict__ ziv,
                                                 u16* __restrict__ id_aug,
                                                 const float* __restrict__ Widv,
                                                 const float* __restrict__ Bidv,
                                                 u16* __restrict__ widv_aug) {
    __shared__ float tile[64][65];
    const int blk = blockIdx.x;
    const int tid = threadIdx.x;
    if (blk < 1250) {  // x_aug: [x | zq | 0]
        const int idx = blk * 256 + tid;
        const int m = idx / 100, c8 = idx - m * 100;
        short8 v;
        if (c8 < 96) {
            const float* s = x + (size_t)m * CD + c8 * 8;
#pragma unroll
            for (int i = 0; i < 8; ++i) v[i] = (short)f2b(s[i]);
        } else if (c8 < 99) {
            const float* s = zq + (size_t)m * 24 + (c8 - 96) * 8;
#pragma unroll
            for (int i = 0; i < 8; ++i) v[i] = (short)f2b(s[i]);
        } else {
#pragma unroll
            for (int i = 0; i < 8; ++i) v[i] = 0;
        }
        *(short8*)(x_aug + (size_t)m * 800 + c8 * 8) = v;
    } else if (blk < 2150) {  // wqkv_aug
        const int idx = (blk - 1250) * 256 + tid;
        const int j = idx / 100, c8 = idx - j * 100;
        short8 v;
        if (c8 < 96) {
            const float* s = Wq + (size_t)j * CD + c8 * 8;
#pragma unroll
            for (int i = 0; i < 8; ++i) v[i] = (short)f2b(s[i]);
        } else if (c8 < 99) {
            const int g = j / CD, c = j - g * CD;
            const int gp = c8 - 96;
#pragma unroll
            for (int i = 0; i < 8; ++i)
                v[i] = (gp == g) ? (short)f2b(0.125f * Bq[((size_t)g * CD + c) * 8 + i])
                                 : (short)0;
        } else {
#pragma unroll
            for (int i = 0; i < 8; ++i) v[i] = 0;
        }
        *(short8*)(wqkv_aug + (size_t)j * 800 + c8 * 8) = v;
    } else if (blk < 2450) {  // wproj_aug
        const int idx = (blk - 2150) * 256 + tid;
        const int j = idx / 100, c8 = idx - j * 100;
        short8 v;
        if (c8 < 96) {
            const float* s = Wp + (size_t)j * CD + c8 * 8;
#pragma unroll
            for (int i = 0; i < 8; ++i) v[i] = (short)f2b(s[i]);
        } else {
            const int e = c8 - 96;
#pragma unroll
            for (int i = 0; i < 8; ++i) v[i] = (short)f2b(Bp[((size_t)e * CD + j) * 8 + i]);
        }
        *(short8*)(wproj_aug + (size_t)j * 800 + c8 * 8) = v;
    } else if (blk < 3650) {  // mem_k -> kseq rows 0..1599
        const int t = (blk - 2450) * 256 + tid;
        const size_t e = (size_t)t * 8;
        const size_t bh = e / (1600 * 64);
        const size_t rem = e - bh * (1600 * 64);
        const float4 f0 = *(const float4*)(mk + e);
        const float4 f1 = *(const float4*)(mk + e + 4);
        short8 s;
        s[0] = (short)f2b(f0.x); s[1] = (short)f2b(f0.y);
        s[2] = (short)f2b(f0.z); s[3] = (short)f2b(f0.w);
        s[4] = (short)f2b(f1.x); s[5] = (short)f2b(f1.y);
        s[6] = (short)f2b(f1.z); s[7] = (short)f2b(f1.w);
        *(short8*)(kseq + bh * (3200 * 64) + rem) = s;
    } else if (blk < 4250) {  // mem_v -> VT cols 0..1599 (transpose)
        const int i = blk - 3650;
        const int kt = i % 25, bh = i / 25;
        const int r = tid >> 2, c0 = (tid & 3) * 16;
        const float* src = mv + ((size_t)bh * 1600 + (size_t)kt * 64 + r) * 64 + c0;
#pragma unroll
        for (int q = 0; q < 4; ++q) {
            const float4 f = *(const float4*)(src + q * 4);
            tile[r][c0 + q * 4 + 0] = f.x;
            tile[r][c0 + q * 4 + 1] = f.y;
            tile[r][c0 + q * 4 + 2] = f.z;
            tile[r][c0 + q * 4 + 3] = f.w;
        }
        __syncthreads();
        short8 s0, s1;
#pragma unroll
        for (int q = 0; q < 8; ++q) s0[q] = (short)f2b(tile[c0 + q][r]);
#pragma unroll
        for (int q = 0; q < 8; ++q) s1[q] = (short)f2b(tile[c0 + 8 + q][r]);
        u16* dst = vt + ((size_t)bh * 64 + r) * 3200 + (size_t)kt * 64 + c0;
        *(short8*)dst = s0;
        *(short8*)(dst + 8) = s1;
    } else if (blk < 4700) {  // id_aug: [id | ziv | 0]
        const int idx = (blk - 4250) * 256 + tid;  // 115200
        const int m = idx / 100, c8 = idx - m * 100;
        short8 v;
        if (c8 < 96) {
            const float* s = id + (size_t)m * CD + c8 * 8;
#pragma unroll
            for (int i = 0; i < 8; ++i) v[i] = (short)f2b(s[i]);
        } else if (c8 == 96) {
            const float* s = ziv + (size_t)m * 8;
#pragma unroll
            for (int i = 0; i < 8; ++i) v[i] = (short)f2b(s[i]);
        } else {
#pragma unroll
            for (int i = 0; i < 8; ++i) v[i] = 0;
        }
        *(short8*)(id_aug + (size_t)m * 800 + c8 * 8) = v;
    } else {  // widv_aug
        const int idx = (blk - 4700) * 256 + tid;  // 76800
        const int j = idx / 100, c8 = idx - j * 100;
        short8 v;
        if (c8 < 96) {
            const float* s = Widv + (size_t)j * CD + c8 * 8;
#pragma unroll
            for (int i = 0; i < 8; ++i) v[i] = (short)f2b(s[i]);
        } else if (c8 == 96) {
#pragma unroll
            for (int i = 0; i < 8; ++i) v[i] = (short)f2b(0.125f * Bidv[(size_t)j * 8 + i]);
        } else {
#pragma unroll
            for (int i = 0; i < 8; ++i) v[i] = 0;
        }
        *(short8*)(widv_aug + (size_t)j * 800 + c8 * 8) = v;
    }
}

// ---------------- MFMA GEMM, K=800 augmented ----------------
template <int MODE>
__global__ __launch_bounds__(MODE == 0 ? 256 : 128) void
gemm16_kernel(const u16* __restrict__ A16, const u16* __restrict__ B16,
              const float* __restrict__ bias, const float* __restrict__ IDK,
              u16* __restrict__ qbh, u16* __restrict__ kseq, u16* __restrict__ vt,
              float* __restrict__ okm, float* __restrict__ ovm,
              float* __restrict__ io) {
    const int tid = threadIdx.x;
    const int lane = tid & 63, wv = tid >> 6;
    const int quad = lane >> 4, n16 = lane & 15;
    int m0, n0;
    if (MODE == 0) {
        m0 = blockIdx.y * 128 + (wv >> 1) * 64;
        n0 = blockIdx.x * 128 + (wv & 1) * 64;
    } else {
        m0 = blockIdx.y * 64;
        n0 = blockIdx.x * 128 + wv * 64;
    }

    f32x4 acc[4][4];
#pragma unroll
    for (int a = 0; a < 4; ++a)
#pragma unroll
        for (int b = 0; b < 4; ++b) acc[a][b] = (f32x4){0.f, 0.f, 0.f, 0.f};

    const u16* ap = A16 + (size_t)(m0 + n16) * 800 + quad * 8;
    const u16* bp = B16 + (size_t)(n0 + n16) * 800 + quad * 8;
#pragma unroll 2
    for (int k0 = 0; k0 < 800; k0 += 32) {
        short8 aA[4], aB[4];
#pragma unroll
        for (int c = 0; c < 4; ++c) {
            aA[c] = *(const short8*)(ap + (size_t)c * 16 * 800 + k0);
            aB[c] = *(const short8*)(bp + (size_t)c * 16 * 800 + k0);
        }
#pragma unroll
        for (int mc = 0; mc < 4; ++mc)
#pragma unroll
            for (int nc = 0; nc < 4; ++nc)
                acc[mc][nc] =
                    __builtin_amdgcn_mfma_f32_16x16x32_bf16(aA[mc], aB[nc], acc[mc][nc], 0, 0, 0);
    }

    if (MODE == 0) {
        const int g = n0 / CD;
        const int hq = (n0 % CD) >> 6;
#pragma unroll
        for (int mc = 0; mc < 4; ++mc) {
#pragma unroll
            for (int r = 0; r < 4; ++r) {
                const int m = m0 + mc * 16 + quad * 4 + r;
                const int b = m / NTOK, n = m - (m / NTOK) * NTOK;
                const size_t bh = (size_t)(b * NH + hq);
                float gate = 0.f;
                if (g == 1 && n < NM) gate = 1.f + tanhf(IDK[(b * NM + n) * NH + hq]);
#pragma unroll
                for (int nc = 0; nc < 4; ++nc) {
                    const int d = nc * 16 + n16;
                    const int j = n0 + d;
                    const float val = acc[mc][nc][r] + bias[j];
                    const size_t om = (bh * NM + n) * 64 + d;
                    if (g == 0) {
                        qbh[(bh * NTOK + n) * 64 + d] = f2b(val * 0.125f);
                    } else if (g == 1) {
                        kseq[(bh * 3200 + 1600 + n) * 64 + d] = f2b(val);
                        if (n < NM) okm[om] = val * gate;
                    } else {
                        float vv = val;
                        if (n < NM) {
                            vv = val + ovm[om];
                            ovm[om] = vv;
                        }
                        vt[(bh * 64 + d) * 3200 + 1600 + n] = f2b(vv);
                    }
                }
            }
        }
    } else if (MODE == 1) {
#pragma unroll
        for (int mc = 0; mc < 4; ++mc) {
#pragma unroll
            for (int r = 0; r < 4; ++r) {
                const int m = m0 + mc * 16 + quad * 4 + r;
#pragma unroll
                for (int nc = 0; nc < 4; ++nc) {
                    const int j = n0 + nc * 16 + n16;
                    io[(size_t)m * CD + j] = acc[mc][nc][r] + bias[j];
                }
            }
        }
    } else {  // MODE 2: idv -> ovm scatter
#pragma unroll
        for (int mc = 0; mc < 4; ++mc) {
#pragma unroll
            for (int r = 0; r < 4; ++r) {
                const int m = m0 + mc * 16 + quad * 4 + r;
                const int b = m / NM, n = m - (m / NM) * NM;
#pragma unroll
                for (int nc = 0; nc < 4; ++nc) {
                    const int j = n0 + nc * 16 + n16;
                    const int h = j >> 6, d = j & 63;
                    ovm[(((size_t)(b * NH + h)) * NM + n) * 64 + d] = acc[mc][nc][r] + bias[j];
                }
            }
        }
    }
}

// ---------------- v11 top-k attention body: batched loads, LDS logits ----------------
template <int L, bool KF32>
__device__ void attn_body(u16* smem,
                          const u16* __restrict__ qbh, const u16* __restrict__ Kb,
                          const float* __restrict__ Kf, const u16* __restrict__ vt,
                          float* __restrict__ aob, int top, int row_start, int krows,
                          int vtoff, int blkx, int bh) {
    constexpr int LP = L + 8;
    constexpr int NCHT = L / 16;
    constexpr int NCH = (NCHT + 7) / 8;
    constexpr bool FULL = (NCHT % 8) == 0;
    constexpr int PAIRS = L / 2;
    constexpr int NPIT = (PAIRS + 63) / 64;
    constexpr bool PFULL = (PAIRS % 64) == 0;
    constexpr int GRP = KF32 ? 2 : 5;   // K-frag prefetch depth (VGPR-bounded)
    u16* wgt = smem;                          // 16*LP u16 (logits -> exp weights)
    u32* hist = (u32*)(smem + 16 * LP);       // 2 replicas x 16 x 256 u32
    float* obuf = (float*)hist;               // alias (PV phase)
    float* rowmax = (float*)(hist + 8192);    // 128
    float* invtot = rowmax + 128;             // 16 (tie-term, then 1/total)
    float* Mrow = invtot + 16;                // 16
    u32* selb = (u32*)(Mrow + 16);            // 16
    u32* Trow = selb + 16;                    // 16
    u32* wantr = Trow + 16;                   // 16

    const int tid = threadIdx.x;
    const int lane = tid & 63, wv = tid >> 6;
    const int quad = lane >> 4, n16 = lane & 15;
    const int rep = (n16 & 1) * 4096;
    const int bb = bh / NH, hh = bh - bb * NH;
    const int r0 = row_start + blkx * 16;

    for (int i = tid; i < 8192; i += 512) hist[i] = 0;

    short8 aQ0, aQ1;
    {
        const u16* qp = qbh + ((size_t)bh * NTOK + r0 + n16) * 64;
        aQ0 = *(const short8*)(qp + quad * 8);
        aQ1 = *(const short8*)(qp + 32 + quad * 8);
    }
    __syncthreads();  // hist zero visible

    // ---- phase 1: QK^T MFMA -> wgt; coarse hist in-flight; GRP-deep prefetch ----
    float rmax[4] = {-3.4e38f, -3.4e38f, -3.4e38f, -3.4e38f};
#pragma unroll
    for (int g = 0; g < NCH; g += GRP) {
        short8 fb0[GRP], fb1[GRP];
#pragma unroll
        for (int i = 0; i < GRP; ++i) {
            const int ci = g + i;
            const int c = wv + ci * 8;
            if (ci < NCH && (FULL || c < NCHT)) {
                const int l0 = c << 4;
                if (KF32) {
                    const float* kp = Kf + ((size_t)bh * krows + l0 + n16) * 64 + quad * 8;
                    const float4 x0 = *(const float4*)kp;
                    const float4 x1 = *(const float4*)(kp + 4);
                    const float4 y0 = *(const float4*)(kp + 32);
                    const float4 y1 = *(const float4*)(kp + 36);
                    short8 t0, t1;
                    t0[0] = (short)f2b(x0.x); t0[1] = (short)f2b(x0.y);
                    t0[2] = (short)f2b(x0.z); t0[3] = (short)f2b(x0.w);
                    t0[4] = (short)f2b(x1.x); t0[5] = (short)f2b(x1.y);
                    t0[6] = (short)f2b(x1.z); t0[7] = (short)f2b(x1.w);
                    t1[0] = (short)f2b(y0.x); t1[1] = (short)f2b(y0.y);
                    t1[2] = (short)f2b(y0.z); t1[3] = (short)f2b(y0.w);
                    t1[4] = (short)f2b(y1.x); t1[5] = (short)f2b(y1.y);
                    t1[6] = (short)f2b(y1.z); t1[7] = (short)f2b(y1.w);
                    fb0[i] = t0; fb1[i] = t1;
                } else {
                    const u16* kp = Kb + ((size_t)bh * krows + l0 + n16) * 64 + quad * 8;
                    fb0[i] = *(const short8*)kp;
                    fb1[i] = *(const short8*)(kp + 32);
                }
            }
        }
#pragma unroll
        for (int i = 0; i < GRP; ++i) {
            const int ci = g + i;
            const int c = wv + ci * 8;
            if (ci < NCH && (FULL || c < NCHT)) {
                const int l0 = c << 4;
                f32x4 d = {0.f, 0.f, 0.f, 0.f};
                d = __builtin_amdgcn_mfma_f32_16x16x32_bf16(aQ0, fb0[i], d, 0, 0, 0);
                d = __builtin_amdgcn_mfma_f32_16x16x32_bf16(aQ1, fb1[i], d, 0, 0, 0);
                const u16 w0 = f2b(d[0]), w1 = f2b(d[1]), w2 = f2b(d[2]), w3 = f2b(d[3]);
#pragma unroll
                for (int r = 0; r < 4; ++r) rmax[r] = fmaxf(rmax[r], d[r]);
                wgt[(size_t)(quad * 4 + 0) * LP + l0 + n16] = w0;
                wgt[(size_t)(quad * 4 + 1) * LP + l0 + n16] = w1;
                wgt[(size_t)(quad * 4 + 2) * LP + l0 + n16] = w2;
                wgt[(size_t)(quad * 4 + 3) * LP + l0 + n16] = w3;
                atomicAdd(&hist[rep + (quad * 4 + 0) * 256 + (flip16((u32)w0) >> 8)], 1u);
                atomicAdd(&hist[rep + (quad * 4 + 1) * 256 + (flip16((u32)w1) >> 8)], 1u);
                atomicAdd(&hist[rep + (quad * 4 + 2) * 256 + (flip16((u32)w2) >> 8)], 1u);
                atomicAdd(&hist[rep + (quad * 4 + 3) * 256 + (flip16((u32)w3) >> 8)], 1u);
            }
        }
    }
#pragma unroll
    for (int off = 1; off < 16; off <<= 1) {
#pragma unroll
        for (int r = 0; r < 4; ++r) rmax[r] = fmaxf(rmax[r], __shfl_xor(rmax[r], off));
    }
    if (n16 == 0) {
#pragma unroll
        for (int r = 0; r < 4; ++r) rowmax[wv * 16 + quad * 4 + r] = rmax[r];
    }
    __syncthreads();

    // ---- scan0: wave per row (rows wv, wv+8) ----
#pragma unroll
    for (int rp = 0; rp < 2; ++rp) {
        const int rr = wv + 8 * rp;
        float M = -3.4e38f;
#pragma unroll
        for (int w = 0; w < 8; ++w) M = fmaxf(M, rowmax[w * 16 + rr]);
        if (lane == 0) Mrow[rr] = M;
        u32 hh4[4];
#pragma unroll
        for (int j = 0; j < 4; ++j)
            hh4[j] = hist[rr * 256 + 4 * lane + j] + hist[4096 + rr * 256 + 4 * lane + j];
        const u32 s = hh4[0] + hh4[1] + hh4[2] + hh4[3];
        u32 sum = s;
#pragma unroll
        for (int off = 1; off < 64; off <<= 1) {
            const u32 t = __shfl_down(sum, off);
            if (lane + off < 64) sum += t;
        }
        int cnt = (int)(sum - s);
        const int want = top;
        for (int j = 3; j >= 0; --j) {
            const int c = (int)hh4[j];
            if (cnt < want && cnt + c >= want) {
                selb[rr] = (u32)(4 * lane + j);
                wantr[rr] = (u32)(want - cnt);
            }
            cnt += c;
        }
    }
    __syncthreads();
    for (int i = tid; i < 8192; i += 512) hist[i] = 0;
    __syncthreads();

    // ---- wave-private per-row: round1 hist -> scan1 -> exp/sum/writeback ----
#pragma unroll
    for (int rp = 0; rp < 2; ++rp) {
        const int rr = wv + 8 * rp;
        const u32* row32 = (const u32*)(wgt + (size_t)rr * LP);
        const u32 sel1 = selb[rr];
        const float M = Mrow[rr];
#pragma unroll
        for (int i = 0; i < NPIT; ++i) {
            if (PFULL || lane + 64 * i < PAIRS) {
                const u32 pr = row32[lane + 64 * i];
                const u32 k0 = flip16(pr & 0xffffu), k1 = flip16(pr >> 16);
                if ((k0 >> 8) == sel1) atomicAdd(&hist[rep + rr * 256 + (k0 & 255u)], 1u);
                if ((k1 >> 8) == sel1) atomicAdd(&hist[rep + rr * 256 + (k1 & 255u)], 1u);
            }
        }
        __threadfence_block();
        {
            u32 hh4[4];
#pragma unroll
            for (int j = 0; j < 4; ++j)
                hh4[j] = hist[rr * 256 + 4 * lane + j] + hist[4096 + rr * 256 + 4 * lane + j];
            const u32 s = hh4[0] + hh4[1] + hh4[2] + hh4[3];
            u32 sum = s;
#pragma unroll
            for (int off = 1; off < 64; off <<= 1) {
                const u32 t = __shfl_down(sum, off);
                if (lane + off < 64) sum += t;
            }
            int cnt = (int)(sum - s);
            const int want = (int)wantr[rr];
            for (int j = 3; j >= 0; --j) {
                const int c = (int)hh4[j];
                if (cnt < want && cnt + c >= want) {
                    const u32 T = (sel1 << 8) | (u32)(4 * lane + j);
                    Trow[rr] = T;
                    invtot[rr] = (float)(want - cnt) * __expf(fminf(key2f(T) - M, 0.f));
                }
                cnt += c;
            }
        }
        __threadfence_block();
        {
            const u32 T = Trow[rr];
            u32* roww = (u32*)(wgt + (size_t)rr * LP);
            float ps = 0.f;
#pragma unroll
            for (int i = 0; i < NPIT; ++i) {
                if (PFULL || lane + 64 * i < PAIRS) {
                    const u32 pr = roww[lane + 64 * i];
                    const u32 k0 = flip16(pr & 0xffffu), k1 = flip16(pr >> 16);
                    float e0 = 0.f, e1 = 0.f;
                    if (k0 >= T) {
                        e0 = __expf(fminf(b2f((u16)(pr & 0xffffu)) - M, 0.f));
                        if (k0 > T) ps += e0;
                    }
                    if (k1 >= T) {
                        e1 = __expf(fminf(b2f((u16)(pr >> 16)) - M, 0.f));
                        if (k1 > T) ps += e1;
                    }
                    roww[lane + 64 * i] = (u32)f2b(e0) | ((u32)f2b(e1) << 16);
                }
            }
            ps = wave_red(ps);
            if (lane == 0) invtot[rr] = 1.f / fmaxf(invtot[rr] + ps, 1e-30f);
        }
    }
    __syncthreads();

    // ---- PV via MFMA; batched VT prefetch; normalize in epilogue ----
    {
        const int half = wv & 1, dc = wv >> 1;
        constexpr int PVI = (L / 2) / 32;
        constexpr int GP = 5;
        const int kbeg = half * (L / 2);
        const u16* vp =
            vt + ((size_t)bh * 64 + dc * 16 + n16) * 3200 + vtoff + quad * 8 + kbeg;
        const u16* wrow2 = wgt + (size_t)n16 * LP + quad * 8 + kbeg;
        f32x4 acc = {0.f, 0.f, 0.f, 0.f};
#pragma unroll
        for (int gg = 0; gg < PVI; gg += GP) {
            short8 bfr[GP];
#pragma unroll
            for (int i = 0; i < GP; ++i)
                if (gg + i < PVI) bfr[i] = *(const short8*)(vp + (gg + i) * 32);
#pragma unroll
            for (int i = 0; i < GP; ++i) {
                if (gg + i < PVI) {
                    const short8 a = *(const short8*)(wrow2 + (gg + i) * 32);
                    acc = __builtin_amdgcn_mfma_f32_16x16x32_bf16(a, bfr[i], acc, 0, 0, 0);
                }
            }
        }
#pragma unroll
        for (int r = 0; r < 4; ++r) {
            const int rowi = quad * 4 + r;
            obuf[(half * 16 + rowi) * 64 + dc * 16 + n16] = acc[r] * invtot[rowi];
        }
    }
    __syncthreads();
#pragma unroll
    for (int ii = 0; ii < 2; ++ii) {
        const int idx = tid + ii * 512;
        const int rowi = idx >> 6, dd = idx & 63;
        aob[((size_t)bb * NTOK + r0 + rowi) * CD + hh * 64 + dd] =
            obuf[rowi * 64 + dd] + obuf[(16 + rowi) * 64 + dd];
    }
}

// Merged dispatch: grid.x = 36 mem blocks + 64 seq blocks, grid.y = 24 (b,h).
// __launch_bounds__(512,2): 8 waves/CU = 2/EU (LDS pins 1 block/CU) -> VGPR cap 256,
// enabling the GRP-deep prefetch (r10's VGPR=32 serialized every K load).
__global__ __launch_bounds__(512, 2) void attn_merged(const u16* __restrict__ qbh,
                                                      const u16* __restrict__ kseq,
                                                      const float* __restrict__ okm,
                                                      const u16* __restrict__ vt,
                                                      float* __restrict__ aob) {
    extern __shared__ __align__(16) u16 smem[];
    if (blockIdx.x < NM / 16) {
        attn_body<NM, true>(smem, qbh, nullptr, okm, vt, aob, NM / 2, 0, NM, 1600,
                            blockIdx.x, blockIdx.y);
    } else {
        attn_body<3200, false>(smem, qbh, kseq, nullptr, vt, aob, 1600, NM, 3200, 0,
                               blockIdx.x - NM / 16, blockIdx.y);
    }
}

// ---------------- proj routing coefficients ----------------
__global__ __launch_bounds__(256) void coef_kernel(const float* __restrict__ aob,
                                                   const float* __restrict__ rW,
                                                   const float* __restrict__ Ap,
                                                   float* __restrict__ coef) {
    __shared__ float rl[8][4];
    __shared__ float rw[8][4];
    const int slot = threadIdx.x >> 5, lane = threadIdx.x & 31;
    const int m = blockIdx.x * 8 + slot;
    const float* xr = aob + (size_t)m * CD;
    const float z = dot768_ff(xr, Ap + (size_t)lane * CD);
    if (lane < 4) rl[slot][lane] = dot768_ff(xr, rW + (size_t)lane * CD);
    __syncthreads();
    if (lane == 0) {
        const float mx = fmaxf(fmaxf(rl[slot][0], rl[slot][1]), fmaxf(rl[slot][2], rl[slot][3]));
        const float e0 = __expf(rl[slot][0] - mx), e1 = __expf(rl[slot][1] - mx);
        const float e2 = __expf(rl[slot][2] - mx), e3 = __expf(rl[slot][3] - mx);
        const float is = 1.f / (e0 + e1 + e2 + e3);
        rw[slot][0] = e0 * is; rw[slot][1] = e1 * is; rw[slot][2] = e2 * is; rw[slot][3] = e3 * is;
    }
    __syncthreads();
    coef[(size_t)m * 32 + lane] = rw[slot][lane >> 3] * z * 0.125f;
}

// ---------------- aob_aug builder ----------------
__global__ __launch_bounds__(256) void cvt_aobaug(const float* __restrict__ aob,
                                                  const float* __restrict__ coef,
                                                  u16* __restrict__ dst) {
    const int idx = blockIdx.x * 256 + threadIdx.x;  // 320000
    const int m = idx / 100, c8 = idx - m * 100;
    short8 v;
    if (c8 < 96) {
        const float* s = aob + (size_t)m * CD + c8 * 8;
#pragma unroll
        for (int i = 0; i < 8; ++i) v[i] = (short)f2b(s[i]);
    } else {
        const float* s = coef + (size_t)m * 32 + (c8 - 96) * 8;
#pragma unroll
        for (int i = 0; i < 8; ++i) v[i] = (short)f2b(s[i]);
    }
    *(short8*)(dst + (size_t)m * 800 + c8 * 8) = v;
}

extern "C" void kernel_launch(void* const* d_in, const int* in_sizes, int n_in,
                              void* d_out, int out_size, void* d_ws, size_t ws_size,
                              hipStream_t stream) {
    const float* x = (const float*)d_in[0];
    const float* id_total = (const float*)d_in[1];
    const float* mem_k = (const float*)d_in[2];
    const float* mem_v = (const float*)d_in[3];
    const float* W_qkv = (const float*)d_in[4];
    const float* b_qkv = (const float*)d_in[5];
    const float* A_qkv = (const float*)d_in[6];
    const float* B_qkv = (const float*)d_in[7];
    const float* W_proj = (const float*)d_in[8];
    const float* b_proj = (const float*)d_in[9];
    const float* routeW_proj = (const float*)d_in[10];
    const float* A_proj = (const float*)d_in[11];
    const float* B_proj = (const float*)d_in[12];
    const float* W_idk = (const float*)d_in[13];
    const float* b_idk = (const float*)d_in[14];
    const float* A_idk = (const float*)d_in[16];
    const float* B_idk = (const float*)d_in[17];
    const float* W_idv = (const float*)d_in[18];
    const float* b_idv = (const float*)d_in[19];
    const float* A_idv = (const float*)d_in[21];
    const float* B_idv = (const float*)d_in[22];

    float* io = (float*)d_out;                       // staging -> aob -> final out
    float* o_km = io + (size_t)BN * NTOK * CD;       // f32 k_m (& mem-attn K); widv_aug first
    float* o_vm = o_km + (size_t)BN * NH * NM * HD;  // f32 ID_V -> v_m

    u16* x_aug = (u16*)io;            // 3200*800 u16
    u16* wqkv_aug = x_aug + 2560000;  // 2304*800 u16 (io region total 8.8 MB <= 9.83 MB)
    u16* widv_aug = (u16*)o_km;       // 768*800 u16 (dead pre-qkv)

    // workspace: 26,613,760 bytes
    u16* qbh = (u16*)d_ws;                  // (B,H,N,64) Q bf16; id_aug first
    u16* kseq = qbh + 2457600;              // (B,H,3200,64); later aob_aug
    u16* vt = kseq + 4915200;               // (B,H,64,3200) V^T
    float* zq = (float*)(vt + 4915200);     // 76800
    float* ziv = zq + 76800;                // 9216
    float* IDK = ziv + 9216;                // 13824
    float* coef = IDK + 13824;              // 102400
    u16* wproj_aug = (u16*)(coef + 102400); // 768*800 u16
    u16* id_aug = qbh;                      // 1152*800 u16 (dead pre-qkv)

    const int smem_seq = 16 * (3200 + 8) * 2 + 33600;  // 136,256
    hipFuncSetAttribute((const void*)attn_merged,
                        hipFuncAttributeMaxDynamicSharedMemorySize, smem_seq);

    small_dots<<<4352, 256, 0, stream>>>(x, A_qkv, zq, id_total, A_idk, A_idv,
                                         W_idk, b_idk, B_idk, ziv, IDK);
    stage_all<<<5000, 256, 0, stream>>>(x, zq, x_aug, W_qkv, B_qkv, wqkv_aug,
                                        W_proj, B_proj, wproj_aug, mem_k, kseq,
                                        mem_v, vt, id_total, ziv, id_aug,
                                        W_idv, B_idv, widv_aug);
    // ID_V via MFMA -> o_vm
    gemm16_kernel<2><<<dim3(6, 18), 128, 0, stream>>>(id_aug, widv_aug, b_idv, nullptr,
                                                      nullptr, nullptr, nullptr, nullptr,
                                                      o_vm, nullptr);
    // qkv via MFMA, fused LoRA + gate/ID_V epilogue
    gemm16_kernel<0><<<dim3(18, 25), 256, 0, stream>>>(x_aug, wqkv_aug, b_qkv, IDK,
                                                       qbh, kseq, vt, o_km, o_vm, nullptr);

    // merged mem+seq top-k attention (one dispatch)
    attn_merged<<<dim3(NM / 16 + NS / 16, BN * NH), 512, smem_seq, stream>>>(
        qbh, kseq, o_km, vt, io);

    coef_kernel<<<400, 256, 0, stream>>>(io, routeW_proj, A_proj, coef);
    cvt_aobaug<<<1250, 256, 0, stream>>>(io, coef, kseq);
    // proj via MFMA, fused routed-LoRA, f32 out in-place
    gemm16_kernel<1><<<dim3(6, 50), 128, 0, stream>>>(kseq, wproj_aug, b_proj, nullptr,
                                                      nullptr, nullptr, nullptr, nullptr,
                                                      nullptr, io);
}

// Round 12
// 626.967 us; speedup vs baseline: 1.0354x; 1.0354x over previous
//
#include <hip/hip_runtime.h>
#include <hip/hip_bf16.h>

#define BN 2
#define NH 12
#define NTOK 1600
#define NM 576
#define NS 1024
#define CD 768
#define HD 64

typedef unsigned short u16;
typedef unsigned int u32;
typedef __attribute__((ext_vector_type(8))) short short8;   // 8 bf16 (4 VGPRs)
typedef __attribute__((ext_vector_type(4))) float f32x4;    // MFMA C/D

__device__ __forceinline__ float fbits(u32 u) { return __uint_as_float(u); }
__device__ __forceinline__ u16 f2b(float f) {  // RNE f32->bf16
    u32 u = __float_as_uint(f);
    u32 r = u + 0x7FFFu + ((u >> 16) & 1u);
    return (u16)(r >> 16);
}
__device__ __forceinline__ float b2f(u16 s) { return fbits(((u32)s) << 16); }
__device__ __forceinline__ u32 flip16(u32 u) {  // order-preserving bf16 -> u16 key
    return (u & 0x8000u) ? (0xFFFFu & ~u) : (u | 0x8000u);
}
__device__ __forceinline__ float key2f(u32 k) {
    u32 b = (k & 0x8000u) ? (k & 0x7FFFu) : (0xFFFFu & ~k);
    return fbits(b << 16);
}
__device__ __forceinline__ float wave_red(float p) {
#pragma unroll
    for (int off = 1; off < 64; off <<= 1) p += __shfl_xor(p, off);
    return p;
}

__device__ __forceinline__ float dot768_ff(const float* __restrict__ a,
                                           const float* __restrict__ b) {
    float s = 0.f;
    for (int c = 0; c < CD; c += 4) {
        float4 fa = *(const float4*)(a + c);
        float4 fb = *(const float4*)(b + c);
        s += fa.x * fb.x + fa.y * fb.y + fa.z * fb.z + fa.w * fb.w;
    }
    return s;
}

// ---------------- small_dots: z24 (x tokens) + ziv/IDK (id tokens) ----------------
__global__ __launch_bounds__(256) void small_dots(const float* __restrict__ x,
                                                  const float* __restrict__ Aq,
                                                  float* __restrict__ zq,
                                                  const float* __restrict__ id,
                                                  const float* __restrict__ Aik,
                                                  const float* __restrict__ Aiv,
                                                  const float* __restrict__ Wik,
                                                  const float* __restrict__ bik,
                                                  const float* __restrict__ Bik,
                                                  float* __restrict__ ziv,
                                                  float* __restrict__ IDK) {
    __shared__ float dres[28];
    const int blk = blockIdx.x;
    const int tid = threadIdx.x, lane = tid & 63, wv = tid >> 6;
    if (blk < 3200) {  // x token: 24 LoRA dots
        const float* xr = x + (size_t)blk * CD;
#pragma unroll
        for (int t = 0; t < 6; ++t) {
            const int q = wv * 6 + t;
            const float* ar = Aq + (size_t)q * CD;
            float p = 0.f;
#pragma unroll
            for (int c = 0; c < 12; ++c) p += xr[lane + c * 64] * ar[lane + c * 64];
            p = wave_red(p);
            if (lane == 0) zq[(size_t)blk * 24 + q] = p;
        }
    } else {  // id token: 8 zik + 8 ziv + 12 W_idk dots, then IDK
        const int m = blk - 3200;
        const float* xr = id + (size_t)m * CD;
#pragma unroll
        for (int t = 0; t < 7; ++t) {
            const int q = wv * 7 + t;
            const float* ar = (q < 8) ? Aik + (size_t)q * CD
                            : (q < 16) ? Aiv + (size_t)(q - 8) * CD
                                       : Wik + (size_t)(q - 16) * CD;
            float p = 0.f;
#pragma unroll
            for (int c = 0; c < 12; ++c) p += xr[lane + c * 64] * ar[lane + c * 64];
            p = wave_red(p);
            if (lane == 0) dres[q] = p;
        }
        __syncthreads();
        if (tid < 8) ziv[(size_t)m * 8 + tid] = dres[8 + tid];
        if (tid < 12) {
            float v = dres[16 + tid] + bik[tid];
            float lo = 0.f;
#pragma unroll
            for (int r = 0; r < 8; ++r) lo += dres[r] * Bik[tid * 8 + r];
            IDK[m * NH + tid] = v + 0.125f * lo;
        }
    }
}

// ---------------- stage_all: every bf16 staging conversion in one launch ----------------
__global__ __launch_bounds__(256) void stage_all(const float* __restrict__ x,
                                                 const float* __restrict__ zq,
                                                 u16* __restrict__ x_aug,
                                                 const float* __restrict__ Wq,
                                                 const float* __restrict__ Bq,
                                                 u16* __restrict__ wqkv_aug,
                                                 const float* __restrict__ Wp,
                                                 const float* __restrict__ Bp,
                                                 u16* __restrict__ wproj_aug,
                                                 const float* __restrict__ mk,
                                                 u16* __restrict__ kseq,
                                                 const float* __restrict__ mv,
                                                 u16* __restrict__ vt,
                                                 const float* __restrict__ id,
                                                 const float* __restrict__ ziv,
                                                 u16* __restrict__ id_aug,
                                                 const float* __restrict__ Widv,
                                                 const float* __restrict__ Bidv,
                                                 u16* __restrict__ widv_aug) {
    __shared__ float tile[64][65];
    const int blk = blockIdx.x;
    const int tid = threadIdx.x;
    if (blk < 1250) {  // x_aug: [x | zq | 0]
        const int idx = blk * 256 + tid;
        const int m = idx / 100, c8 = idx - m * 100;
        short8 v;
        if (c8 < 96) {
            const float* s = x + (size_t)m * CD + c8 * 8;
#pragma unroll
            for (int i = 0; i < 8; ++i) v[i] = (short)f2b(s[i]);
        } else if (c8 < 99) {
            const float* s = zq + (size_t)m * 24 + (c8 - 96) * 8;
#pragma unroll
            for (int i = 0; i < 8; ++i) v[i] = (short)f2b(s[i]);
        } else {
#pragma unroll
            for (int i = 0; i < 8; ++i) v[i] = 0;
        }
        *(short8*)(x_aug + (size_t)m * 800 + c8 * 8) = v;
    } else if (blk < 2150) {  // wqkv_aug
        const int idx = (blk - 1250) * 256 + tid;
        const int j = idx / 100, c8 = idx - j * 100;
        short8 v;
        if (c8 < 96) {
            const float* s = Wq + (size_t)j * CD + c8 * 8;
#pragma unroll
            for (int i = 0; i < 8; ++i) v[i] = (short)f2b(s[i]);
        } else if (c8 < 99) {
            const int g = j / CD, c = j - g * CD;
            const int gp = c8 - 96;
#pragma unroll
            for (int i = 0; i < 8; ++i)
                v[i] = (gp == g) ? (short)f2b(0.125f * Bq[((size_t)g * CD + c) * 8 + i])
                                 : (short)0;
        } else {
#pragma unroll
            for (int i = 0; i < 8; ++i) v[i] = 0;
        }
        *(short8*)(wqkv_aug + (size_t)j * 800 + c8 * 8) = v;
    } else if (blk < 2450) {  // wproj_aug
        const int idx = (blk - 2150) * 256 + tid;
        const int j = idx / 100, c8 = idx - j * 100;
        short8 v;
        if (c8 < 96) {
            const float* s = Wp + (size_t)j * CD + c8 * 8;
#pragma unroll
            for (int i = 0; i < 8; ++i) v[i] = (short)f2b(s[i]);
        } else {
            const int e = c8 - 96;
#pragma unroll
            for (int i = 0; i < 8; ++i) v[i] = (short)f2b(Bp[((size_t)e * CD + j) * 8 + i]);
        }
        *(short8*)(wproj_aug + (size_t)j * 800 + c8 * 8) = v;
    } else if (blk < 3650) {  // mem_k -> kseq rows 0..1599
        const int t = (blk - 2450) * 256 + tid;
        const size_t e = (size_t)t * 8;
        const size_t bh = e / (1600 * 64);
        const size_t rem = e - bh * (1600 * 64);
        const float4 f0 = *(const float4*)(mk + e);
        const float4 f1 = *(const float4*)(mk + e + 4);
        short8 s;
        s[0] = (short)f2b(f0.x); s[1] = (short)f2b(f0.y);
        s[2] = (short)f2b(f0.z); s[3] = (short)f2b(f0.w);
        s[4] = (short)f2b(f1.x); s[5] = (short)f2b(f1.y);
        s[6] = (short)f2b(f1.z); s[7] = (short)f2b(f1.w);
        *(short8*)(kseq + bh * (3200 * 64) + rem) = s;
    } else if (blk < 4250) {  // mem_v -> VT cols 0..1599 (transpose)
        const int i = blk - 3650;
        const int kt = i % 25, bh = i / 25;
        const int r = tid >> 2, c0 = (tid & 3) * 16;
        const float* src = mv + ((size_t)bh * 1600 + (size_t)kt * 64 + r) * 64 + c0;
#pragma unroll
        for (int q = 0; q < 4; ++q) {
            const float4 f = *(const float4*)(src + q * 4);
            tile[r][c0 + q * 4 + 0] = f.x;
            tile[r][c0 + q * 4 + 1] = f.y;
            tile[r][c0 + q * 4 + 2] = f.z;
            tile[r][c0 + q * 4 + 3] = f.w;
        }
        __syncthreads();
        short8 s0, s1;
#pragma unroll
        for (int q = 0; q < 8; ++q) s0[q] = (short)f2b(tile[c0 + q][r]);
#pragma unroll
        for (int q = 0; q < 8; ++q) s1[q] = (short)f2b(tile[c0 + 8 + q][r]);
        u16* dst = vt + ((size_t)bh * 64 + r) * 3200 + (size_t)kt * 64 + c0;
        *(short8*)dst = s0;
        *(short8*)(dst + 8) = s1;
    } else if (blk < 4700) {  // id_aug: [id | ziv | 0]
        const int idx = (blk - 4250) * 256 + tid;  // 115200
        const int m = idx / 100, c8 = idx - m * 100;
        short8 v;
        if (c8 < 96) {
            const float* s = id + (size_t)m * CD + c8 * 8;
#pragma unroll
            for (int i = 0; i < 8; ++i) v[i] = (short)f2b(s[i]);
        } else if (c8 == 96) {
            const float* s = ziv + (size_t)m * 8;
#pragma unroll
            for (int i = 0; i < 8; ++i) v[i] = (short)f2b(s[i]);
        } else {
#pragma unroll
            for (int i = 0; i < 8; ++i) v[i] = 0;
        }
        *(short8*)(id_aug + (size_t)m * 800 + c8 * 8) = v;
    } else {  // widv_aug
        const int idx = (blk - 4700) * 256 + tid;  // 76800
        const int j = idx / 100, c8 = idx - j * 100;
        short8 v;
        if (c8 < 96) {
            const float* s = Widv + (size_t)j * CD + c8 * 8;
#pragma unroll
            for (int i = 0; i < 8; ++i) v[i] = (short)f2b(s[i]);
        } else if (c8 == 96) {
#pragma unroll
            for (int i = 0; i < 8; ++i) v[i] = (short)f2b(0.125f * Bidv[(size_t)j * 8 + i]);
        } else {
#pragma unroll
            for (int i = 0; i < 8; ++i) v[i] = 0;
        }
        *(short8*)(widv_aug + (size_t)j * 800 + c8 * 8) = v;
    }
}

// ---------------- MFMA GEMM, K=800 augmented ----------------
template <int MODE>
__global__ __launch_bounds__(MODE == 0 ? 256 : 128) void
gemm16_kernel(const u16* __restrict__ A16, const u16* __restrict__ B16,
              const float* __restrict__ bias, const float* __restrict__ IDK,
              u16* __restrict__ qbh, u16* __restrict__ kseq, u16* __restrict__ vt,
              float* __restrict__ okm, float* __restrict__ ovm,
              float* __restrict__ io) {
    const int tid = threadIdx.x;
    const int lane = tid & 63, wv = tid >> 6;
    const int quad = lane >> 4, n16 = lane & 15;
    int m0, n0;
    if (MODE == 0) {
        m0 = blockIdx.y * 128 + (wv >> 1) * 64;
        n0 = blockIdx.x * 128 + (wv & 1) * 64;
    } else {
        m0 = blockIdx.y * 64;
        n0 = blockIdx.x * 128 + wv * 64;
    }

    f32x4 acc[4][4];
#pragma unroll
    for (int a = 0; a < 4; ++a)
#pragma unroll
        for (int b = 0; b < 4; ++b) acc[a][b] = (f32x4){0.f, 0.f, 0.f, 0.f};

    const u16* ap = A16 + (size_t)(m0 + n16) * 800 + quad * 8;
    const u16* bp = B16 + (size_t)(n0 + n16) * 800 + quad * 8;
#pragma unroll 2
    for (int k0 = 0; k0 < 800; k0 += 32) {
        short8 aA[4], aB[4];
#pragma unroll
        for (int c = 0; c < 4; ++c) {
            aA[c] = *(const short8*)(ap + (size_t)c * 16 * 800 + k0);
            aB[c] = *(const short8*)(bp + (size_t)c * 16 * 800 + k0);
        }
#pragma unroll
        for (int mc = 0; mc < 4; ++mc)
#pragma unroll
            for (int nc = 0; nc < 4; ++nc)
                acc[mc][nc] =
                    __builtin_amdgcn_mfma_f32_16x16x32_bf16(aA[mc], aB[nc], acc[mc][nc], 0, 0, 0);
    }

    if (MODE == 0) {
        const int g = n0 / CD;
        const int hq = (n0 % CD) >> 6;
#pragma unroll
        for (int mc = 0; mc < 4; ++mc) {
#pragma unroll
            for (int r = 0; r < 4; ++r) {
                const int m = m0 + mc * 16 + quad * 4 + r;
                const int b = m / NTOK, n = m - (m / NTOK) * NTOK;
                const size_t bh = (size_t)(b * NH + hq);
                float gate = 0.f;
                if (g == 1 && n < NM) gate = 1.f + tanhf(IDK[(b * NM + n) * NH + hq]);
#pragma unroll
                for (int nc = 0; nc < 4; ++nc) {
                    const int d = nc * 16 + n16;
                    const int j = n0 + d;
                    const float val = acc[mc][nc][r] + bias[j];
                    const size_t om = (bh * NM + n) * 64 + d;
                    if (g == 0) {
                        qbh[(bh * NTOK + n) * 64 + d] = f2b(val * 0.125f);
                    } else if (g == 1) {
                        kseq[(bh * 3200 + 1600 + n) * 64 + d] = f2b(val);
                        if (n < NM) okm[om] = val * gate;
                    } else {
                        float vv = val;
                        if (n < NM) {
                            vv = val + ovm[om];
                            ovm[om] = vv;
                        }
                        vt[(bh * 64 + d) * 3200 + 1600 + n] = f2b(vv);
                    }
                }
            }
        }
    } else if (MODE == 1) {
#pragma unroll
        for (int mc = 0; mc < 4; ++mc) {
#pragma unroll
            for (int r = 0; r < 4; ++r) {
                const int m = m0 + mc * 16 + quad * 4 + r;
#pragma unroll
                for (int nc = 0; nc < 4; ++nc) {
                    const int j = n0 + nc * 16 + n16;
                    io[(size_t)m * CD + j] = acc[mc][nc][r] + bias[j];
                }
            }
        }
    } else {  // MODE 2: idv -> ovm scatter
#pragma unroll
        for (int mc = 0; mc < 4; ++mc) {
#pragma unroll
            for (int r = 0; r < 4; ++r) {
                const int m = m0 + mc * 16 + quad * 4 + r;
                const int b = m / NM, n = m - (m / NM) * NM;
#pragma unroll
                for (int nc = 0; nc < 4; ++nc) {
                    const int j = n0 + nc * 16 + n16;
                    const int h = j >> 6, d = j & 63;
                    ovm[(((size_t)(b * NH + h)) * NM + n) * 64 + d] = acc[mc][nc][r] + bias[j];
                }
            }
        }
    }
}

// ---------------- v12 top-k attention: XCD-swizzled grid, batched loads ----------------
// 1-D grid, id = bh + 24*qtile -> XCD = id%8 = bh%8 (24%8==0): all q-tiles of one
// (b,h) share an XCD; 3 bh/XCD => K+V working set 2.4 MB < 4 MB L2. r11's (x=tile,
// y=bh) spread every bh across all XCDs -> 93 MB HBM fetch at ~300 GB/s = the
// entire runtime.
template <int L, bool KF32>
__global__ __launch_bounds__(512, 2) void attn12_kernel(const u16* __restrict__ qbh,
                                                        const u16* __restrict__ Kb,
                                                        const float* __restrict__ Kf,
                                                        const u16* __restrict__ vt,
                                                        float* __restrict__ aob,
                                                        int top, int row_start, int krows,
                                                        int vtoff) {
    constexpr int LP = L + 8;
    constexpr int NCHT = L / 16;
    constexpr int NCH = (NCHT + 7) / 8;
    constexpr bool FULL = (NCHT % 8) == 0;
    constexpr int PAIRS = L / 2;
    constexpr int NPIT = (PAIRS + 63) / 64;
    constexpr bool PFULL = (PAIRS % 64) == 0;
    constexpr int GRP = KF32 ? 2 : 5;   // K-frag prefetch depth
    extern __shared__ __align__(16) u16 smem[];
    u16* wgt = smem;                          // 16*LP u16 (logits -> exp weights)
    u32* hist = (u32*)(smem + 16 * LP);       // 2 replicas x 16 x 256 u32
    float* obuf = (float*)hist;               // alias (PV phase)
    float* rowmax = (float*)(hist + 8192);    // 128
    float* invtot = rowmax + 128;             // 16 (tie-term, then 1/total)
    float* Mrow = invtot + 16;                // 16
    u32* selb = (u32*)(Mrow + 16);            // 16
    u32* Trow = selb + 16;                    // 16
    u32* wantr = Trow + 16;                   // 16

    const int tid = threadIdx.x;
    const int lane = tid & 63, wv = tid >> 6;
    const int quad = lane >> 4, n16 = lane & 15;
    const int rep = (n16 & 1) * 4096;
    const int bh = blockIdx.x % (BN * NH);    // XCD = bh % 8
    const int blkx = blockIdx.x / (BN * NH);
    const int bb = bh / NH, hh = bh - bb * NH;
    const int r0 = row_start + blkx * 16;

    for (int i = tid; i < 8192; i += 512) hist[i] = 0;

    short8 aQ0, aQ1;
    {
        const u16* qp = qbh + ((size_t)bh * NTOK + r0 + n16) * 64;
        aQ0 = *(const short8*)(qp + quad * 8);
        aQ1 = *(const short8*)(qp + 32 + quad * 8);
    }
    __syncthreads();  // hist zero visible

    // ---- phase 1: QK^T MFMA -> wgt; coarse hist in-flight; GRP-deep prefetch ----
    float rmax[4] = {-3.4e38f, -3.4e38f, -3.4e38f, -3.4e38f};
#pragma unroll
    for (int g = 0; g < NCH; g += GRP) {
        short8 fb0[GRP], fb1[GRP];
#pragma unroll
        for (int i = 0; i < GRP; ++i) {
            const int ci = g + i;
            const int c = wv + ci * 8;
            if (ci < NCH && (FULL || c < NCHT)) {
                const int l0 = c << 4;
                if (KF32) {
                    const float* kp = Kf + ((size_t)bh * krows + l0 + n16) * 64 + quad * 8;
                    const float4 x0 = *(const float4*)kp;
                    const float4 x1 = *(const float4*)(kp + 4);
                    const float4 y0 = *(const float4*)(kp + 32);
                    const float4 y1 = *(const float4*)(kp + 36);
                    short8 t0, t1;
                    t0[0] = (short)f2b(x0.x); t0[1] = (short)f2b(x0.y);
                    t0[2] = (short)f2b(x0.z); t0[3] = (short)f2b(x0.w);
                    t0[4] = (short)f2b(x1.x); t0[5] = (short)f2b(x1.y);
                    t0[6] = (short)f2b(x1.z); t0[7] = (short)f2b(x1.w);
                    t1[0] = (short)f2b(y0.x); t1[1] = (short)f2b(y0.y);
                    t1[2] = (short)f2b(y0.z); t1[3] = (short)f2b(y0.w);
                    t1[4] = (short)f2b(y1.x); t1[5] = (short)f2b(y1.y);
                    t1[6] = (short)f2b(y1.z); t1[7] = (short)f2b(y1.w);
                    fb0[i] = t0; fb1[i] = t1;
                } else {
                    const u16* kp = Kb + ((size_t)bh * krows + l0 + n16) * 64 + quad * 8;
                    fb0[i] = *(const short8*)kp;
                    fb1[i] = *(const short8*)(kp + 32);
                }
            }
        }
#pragma unroll
        for (int i = 0; i < GRP; ++i) {
            const int ci = g + i;
            const int c = wv + ci * 8;
            if (ci < NCH && (FULL || c < NCHT)) {
                const int l0 = c << 4;
                f32x4 d = {0.f, 0.f, 0.f, 0.f};
                d = __builtin_amdgcn_mfma_f32_16x16x32_bf16(aQ0, fb0[i], d, 0, 0, 0);
                d = __builtin_amdgcn_mfma_f32_16x16x32_bf16(aQ1, fb1[i], d, 0, 0, 0);
                const u16 w0 = f2b(d[0]), w1 = f2b(d[1]), w2 = f2b(d[2]), w3 = f2b(d[3]);
#pragma unroll
                for (int r = 0; r < 4; ++r) rmax[r] = fmaxf(rmax[r], d[r]);
                wgt[(size_t)(quad * 4 + 0) * LP + l0 + n16] = w0;
                wgt[(size_t)(quad * 4 + 1) * LP + l0 + n16] = w1;
                wgt[(size_t)(quad * 4 + 2) * LP + l0 + n16] = w2;
                wgt[(size_t)(quad * 4 + 3) * LP + l0 + n16] = w3;
                atomicAdd(&hist[rep + (quad * 4 + 0) * 256 + (flip16((u32)w0) >> 8)], 1u);
                atomicAdd(&hist[rep + (quad * 4 + 1) * 256 + (flip16((u32)w1) >> 8)], 1u);
                atomicAdd(&hist[rep + (quad * 4 + 2) * 256 + (flip16((u32)w2) >> 8)], 1u);
                atomicAdd(&hist[rep + (quad * 4 + 3) * 256 + (flip16((u32)w3) >> 8)], 1u);
            }
        }
    }
#pragma unroll
    for (int off = 1; off < 16; off <<= 1) {
#pragma unroll
        for (int r = 0; r < 4; ++r) rmax[r] = fmaxf(rmax[r], __shfl_xor(rmax[r], off));
    }
    if (n16 == 0) {
#pragma unroll
        for (int r = 0; r < 4; ++r) rowmax[wv * 16 + quad * 4 + r] = rmax[r];
    }
    __syncthreads();

    // ---- scan0: wave per row (rows wv, wv+8) ----
#pragma unroll
    for (int rp = 0; rp < 2; ++rp) {
        const int rr = wv + 8 * rp;
        float M = -3.4e38f;
#pragma unroll
        for (int w = 0; w < 8; ++w) M = fmaxf(M, rowmax[w * 16 + rr]);
        if (lane == 0) Mrow[rr] = M;
        u32 hh4[4];
#pragma unroll
        for (int j = 0; j < 4; ++j)
            hh4[j] = hist[rr * 256 + 4 * lane + j] + hist[4096 + rr * 256 + 4 * lane + j];
        const u32 s = hh4[0] + hh4[1] + hh4[2] + hh4[3];
        u32 sum = s;
#pragma unroll
        for (int off = 1; off < 64; off <<= 1) {
            const u32 t = __shfl_down(sum, off);
            if (lane + off < 64) sum += t;
        }
        int cnt = (int)(sum - s);
        const int want = top;
        for (int j = 3; j >= 0; --j) {
            const int c = (int)hh4[j];
            if (cnt < want && cnt + c >= want) {
                selb[rr] = (u32)(4 * lane + j);
                wantr[rr] = (u32)(want - cnt);
            }
            cnt += c;
        }
    }
    __syncthreads();
    for (int i = tid; i < 8192; i += 512) hist[i] = 0;
    __syncthreads();

    // ---- wave-private per-row: round1 hist -> scan1 -> exp/sum/writeback ----
#pragma unroll
    for (int rp = 0; rp < 2; ++rp) {
        const int rr = wv + 8 * rp;
        const u32* row32 = (const u32*)(wgt + (size_t)rr * LP);
        const u32 sel1 = selb[rr];
        const float M = Mrow[rr];
#pragma unroll
        for (int i = 0; i < NPIT; ++i) {
            if (PFULL || lane + 64 * i < PAIRS) {
                const u32 pr = row32[lane + 64 * i];
                const u32 k0 = flip16(pr & 0xffffu), k1 = flip16(pr >> 16);
                if ((k0 >> 8) == sel1) atomicAdd(&hist[rep + rr * 256 + (k0 & 255u)], 1u);
                if ((k1 >> 8) == sel1) atomicAdd(&hist[rep + rr * 256 + (k1 & 255u)], 1u);
            }
        }
        __threadfence_block();
        {
            u32 hh4[4];
#pragma unroll
            for (int j = 0; j < 4; ++j)
                hh4[j] = hist[rr * 256 + 4 * lane + j] + hist[4096 + rr * 256 + 4 * lane + j];
            const u32 s = hh4[0] + hh4[1] + hh4[2] + hh4[3];
            u32 sum = s;
#pragma unroll
            for (int off = 1; off < 64; off <<= 1) {
                const u32 t = __shfl_down(sum, off);
                if (lane + off < 64) sum += t;
            }
            int cnt = (int)(sum - s);
            const int want = (int)wantr[rr];
            for (int j = 3; j >= 0; --j) {
                const int c = (int)hh4[j];
                if (cnt < want && cnt + c >= want) {
                    const u32 T = (sel1 << 8) | (u32)(4 * lane + j);
                    Trow[rr] = T;
                    invtot[rr] = (float)(want - cnt) * __expf(fminf(key2f(T) - M, 0.f));
                }
                cnt += c;
            }
        }
        __threadfence_block();
        {
            const u32 T = Trow[rr];
            u32* roww = (u32*)(wgt + (size_t)rr * LP);
            float ps = 0.f;
#pragma unroll
            for (int i = 0; i < NPIT; ++i) {
                if (PFULL || lane + 64 * i < PAIRS) {
                    const u32 pr = roww[lane + 64 * i];
                    const u32 k0 = flip16(pr & 0xffffu), k1 = flip16(pr >> 16);
                    float e0 = 0.f, e1 = 0.f;
                    if (k0 >= T) {
                        e0 = __expf(fminf(b2f((u16)(pr & 0xffffu)) - M, 0.f));
                        if (k0 > T) ps += e0;
                    }
                    if (k1 >= T) {
                        e1 = __expf(fminf(b2f((u16)(pr >> 16)) - M, 0.f));
                        if (k1 > T) ps += e1;
                    }
                    roww[lane + 64 * i] = (u32)f2b(e0) | ((u32)f2b(e1) << 16);
                }
            }
            ps = wave_red(ps);
            if (lane == 0) invtot[rr] = 1.f / fmaxf(invtot[rr] + ps, 1e-30f);
        }
    }
    __syncthreads();

    // ---- PV via MFMA; batched VT prefetch; normalize in epilogue ----
    {
        const int half = wv & 1, dc = wv >> 1;
        constexpr int PVI = (L / 2) / 32;
        constexpr int GP = 5;
        const int kbeg = half * (L / 2);
        const u16* vp =
            vt + ((size_t)bh * 64 + dc * 16 + n16) * 3200 + vtoff + quad * 8 + kbeg;
        const u16* wrow2 = wgt + (size_t)n16 * LP + quad * 8 + kbeg;
        f32x4 acc = {0.f, 0.f, 0.f, 0.f};
#pragma unroll
        for (int gg = 0; gg < PVI; gg += GP) {
            short8 bfr[GP];
#pragma unroll
            for (int i = 0; i < GP; ++i)
                if (gg + i < PVI) bfr[i] = *(const short8*)(vp + (gg + i) * 32);
#pragma unroll
            for (int i = 0; i < GP; ++i) {
                if (gg + i < PVI) {
                    const short8 a = *(const short8*)(wrow2 + (gg + i) * 32);
                    acc = __builtin_amdgcn_mfma_f32_16x16x32_bf16(a, bfr[i], acc, 0, 0, 0);
                }
            }
        }
#pragma unroll
        for (int r = 0; r < 4; ++r) {
            const int rowi = quad * 4 + r;
            obuf[(half * 16 + rowi) * 64 + dc * 16 + n16] = acc[r] * invtot[rowi];
        }
    }
    __syncthreads();
#pragma unroll
    for (int ii = 0; ii < 2; ++ii) {
        const int idx = tid + ii * 512;
        const int rowi = idx >> 6, dd = idx & 63;
        aob[((size_t)bb * NTOK + r0 + rowi) * CD + hh * 64 + dd] =
            obuf[rowi * 64 + dd] + obuf[(16 + rowi) * 64 + dd];
    }
}

// ---------------- proj routing coefficients ----------------
__global__ __launch_bounds__(256) void coef_kernel(const float* __restrict__ aob,
                                                   const float* __restrict__ rW,
                                                   const float* __restrict__ Ap,
                                                   float* __restrict__ coef) {
    __shared__ float rl[8][4];
    __shared__ float rw[8][4];
    const int slot = threadIdx.x >> 5, lane = threadIdx.x & 31;
    const int m = blockIdx.x * 8 + slot;
    const float* xr = aob + (size_t)m * CD;
    const float z = dot768_ff(xr, Ap + (size_t)lane * CD);
    if (lane < 4) rl[slot][lane] = dot768_ff(xr, rW + (size_t)lane * CD);
    __syncthreads();
    if (lane == 0) {
        const float mx = fmaxf(fmaxf(rl[slot][0], rl[slot][1]), fmaxf(rl[slot][2], rl[slot][3]));
        const float e0 = __expf(rl[slot][0] - mx), e1 = __expf(rl[slot][1] - mx);
        const float e2 = __expf(rl[slot][2] - mx), e3 = __expf(rl[slot][3] - mx);
        const float is = 1.f / (e0 + e1 + e2 + e3);
        rw[slot][0] = e0 * is; rw[slot][1] = e1 * is; rw[slot][2] = e2 * is; rw[slot][3] = e3 * is;
    }
    __syncthreads();
    coef[(size_t)m * 32 + lane] = rw[slot][lane >> 3] * z * 0.125f;
}

// ---------------- aob_aug builder ----------------
__global__ __launch_bounds__(256) void cvt_aobaug(const float* __restrict__ aob,
                                                  const float* __restrict__ coef,
                                                  u16* __restrict__ dst) {
    const int idx = blockIdx.x * 256 + threadIdx.x;  // 320000
    const int m = idx / 100, c8 = idx - m * 100;
    short8 v;
    if (c8 < 96) {
        const float* s = aob + (size_t)m * CD + c8 * 8;
#pragma unroll
        for (int i = 0; i < 8; ++i) v[i] = (short)f2b(s[i]);
    } else {
        const float* s = coef + (size_t)m * 32 + (c8 - 96) * 8;
#pragma unroll
        for (int i = 0; i < 8; ++i) v[i] = (short)f2b(s[i]);
    }
    *(short8*)(dst + (size_t)m * 800 + c8 * 8) = v;
}

extern "C" void kernel_launch(void* const* d_in, const int* in_sizes, int n_in,
                              void* d_out, int out_size, void* d_ws, size_t ws_size,
                              hipStream_t stream) {
    const float* x = (const float*)d_in[0];
    const float* id_total = (const float*)d_in[1];
    const float* mem_k = (const float*)d_in[2];
    const float* mem_v = (const float*)d_in[3];
    const float* W_qkv = (const float*)d_in[4];
    const float* b_qkv = (const float*)d_in[5];
    const float* A_qkv = (const float*)d_in[6];
    const float* B_qkv = (const float*)d_in[7];
    const float* W_proj = (const float*)d_in[8];
    const float* b_proj = (const float*)d_in[9];
    const float* routeW_proj = (const float*)d_in[10];
    const float* A_proj = (const float*)d_in[11];
    const float* B_proj = (const float*)d_in[12];
    const float* W_idk = (const float*)d_in[13];
    const float* b_idk = (const float*)d_in[14];
    const float* A_idk = (const float*)d_in[16];
    const float* B_idk = (const float*)d_in[17];
    const float* W_idv = (const float*)d_in[18];
    const float* b_idv = (const float*)d_in[19];
    const float* A_idv = (const float*)d_in[21];
    const float* B_idv = (const float*)d_in[22];

    float* io = (float*)d_out;                       // staging -> aob -> final out
    float* o_km = io + (size_t)BN * NTOK * CD;       // f32 k_m (& mem-attn K); widv_aug first
    float* o_vm = o_km + (size_t)BN * NH * NM * HD;  // f32 ID_V -> v_m

    u16* x_aug = (u16*)io;            // 3200*800 u16
    u16* wqkv_aug = x_aug + 2560000;  // 2304*800 u16 (io region total 8.8 MB <= 9.83 MB)
    u16* widv_aug = (u16*)o_km;       // 768*800 u16 (dead pre-qkv)

    // workspace: 26,613,760 bytes
    u16* qbh = (u16*)d_ws;                  // (B,H,N,64) Q bf16; id_aug first
    u16* kseq = qbh + 2457600;              // (B,H,3200,64); later aob_aug
    u16* vt = kseq + 4915200;               // (B,H,64,3200) V^T
    float* zq = (float*)(vt + 4915200);     // 76800
    float* ziv = zq + 76800;                // 9216
    float* IDK = ziv + 9216;                // 13824
    float* coef = IDK + 13824;              // 102400
    u16* wproj_aug = (u16*)(coef + 102400); // 768*800 u16
    u16* id_aug = qbh;                      // 1152*800 u16 (dead pre-qkv)

    const int smem_seq = 16 * (3200 + 8) * 2 + 33600;  // 136,256
    const int smem_mem = 16 * (NM + 8) * 2 + 33600;    // 52,288
    hipFuncSetAttribute((const void*)attn12_kernel<3200, false>,
                        hipFuncAttributeMaxDynamicSharedMemorySize, smem_seq);
    hipFuncSetAttribute((const void*)attn12_kernel<NM, true>,
                        hipFuncAttributeMaxDynamicSharedMemorySize, smem_mem);

    small_dots<<<4352, 256, 0, stream>>>(x, A_qkv, zq, id_total, A_idk, A_idv,
                                         W_idk, b_idk, B_idk, ziv, IDK);
    stage_all<<<5000, 256, 0, stream>>>(x, zq, x_aug, W_qkv, B_qkv, wqkv_aug,
                                        W_proj, B_proj, wproj_aug, mem_k, kseq,
                                        mem_v, vt, id_total, ziv, id_aug,
                                        W_idv, B_idv, widv_aug);
    // ID_V via MFMA -> o_vm
    gemm16_kernel<2><<<dim3(6, 18), 128, 0, stream>>>(id_aug, widv_aug, b_idv, nullptr,
                                                      nullptr, nullptr, nullptr, nullptr,
                                                      o_vm, nullptr);
    // qkv via MFMA, fused LoRA + gate/ID_V epilogue
    gemm16_kernel<0><<<dim3(18, 25), 256, 0, stream>>>(x_aug, wqkv_aug, b_qkv, IDK,
                                                       qbh, kseq, vt, o_km, o_vm, nullptr);

    // memory attention: L=576, top=288, K=o_km (f32), V=VT cols 1600..2175
    attn12_kernel<NM, true><<<(NM / 16) * BN * NH, 512, smem_mem, stream>>>(
        qbh, nullptr, o_km, vt, io, NM / 2, 0, NM, 1600);
    // seq attention: L=3200, top=1600, K=kseq, V=VT cols 0..3199 (XCD-swizzled grid)
    attn12_kernel<3200, false><<<(NS / 16) * BN * NH, 512, smem_seq, stream>>>(
        qbh, kseq, nullptr, vt, io, 1600, NM, 3200, 0);

    coef_kernel<<<400, 256, 0, stream>>>(io, routeW_proj, A_proj, coef);
    cvt_aobaug<<<1250, 256, 0, stream>>>(io, coef, kseq);
    // proj via MFMA, fused routed-LoRA, f32 out in-place
    gemm16_kernel<1><<<dim3(6, 50), 128, 0, stream>>>(kseq, wproj_aug, b_proj, nullptr,
                                                      nullptr, nullptr, nullptr, nullptr,
                                                      nullptr, io);
}